// Round 1
// baseline (2821.984 us; speedup 1.0000x reference)
//
#include <hip/hip_runtime.h>
#include <hip/hip_bf16.h>

// ============================================================================
// MLA forward, fp32 correctness-first baseline.
// Pipeline:
//  1 sgemm  q_a  = hidden @ q_a_w            [4096,1536]
//  2 sgemm  ckv  = hidden @ kv_a_w           [4096,192]
//  3 rmsq   q_a  = rms_norm(q_a)*w           (in place, width 1536)
//  4 rmskv  ckv[:, :128] = rms_norm(...)*w   (in place, width 128)
//  5 ropek  ckv[:,128:192] roped             (in place)
//  6 sgemm  q    = q_a @ q_b_w               [4096,3072]
//  7 sgemm  kv   = ckv[:, :128] @ kv_b_w     [4096,3072]
//  8 ropeq  q roped + whole q pre-scaled by 192^-0.5 (in place)
//  9 scores raw scores -> weights region of d_out (537 MB)
// 10 softmax row-wise in place on weights
// 11 pv     attn = weights @ v               [4096,1024]
// 12 sgemm  out  = attn @ o_w -> d_out       [4096,2048]
// Workspace: [q_a|attn][q][ckv][kv] = 129 MB.
// ============================================================================

namespace {

constexpr int kB = 2;
constexpr int kS = 2048;
constexpr int kHid = 2048;
constexpr int kH = 16;
constexpr int kQLora = 1536;
constexpr int kCkvDim = 192;              // KV_LORA(128) + ROPE(64)
constexpr int kQDim = 3072;               // H * 192
constexpr int kKVDim = 3072;              // H * (128 + 64)
constexpr int kBS = kB * kS;              // 4096
constexpr float kEps = 1e-6f;
constexpr float kScaling = 0.07216878364870322f;  // 192^-0.5

// ---------------- generic row-major SGEMM: C = A @ B ------------------------
// Grid: x = N/BN, y = M/BM. M,N,K must divide the tile sizes (they do here).
template <int BM, int BN, int BK, int TM, int TN>
__global__ __launch_bounds__((BM / TM) * (BN / TN)) void sgemm_kernel(
    const float* __restrict__ A, int lda, const float* __restrict__ Bm, int ldb,
    float* __restrict__ C, int ldc, int K) {
  constexpr int THREADS = (BM / TM) * (BN / TN);
  __shared__ float As[BK][BM];
  __shared__ float Bs[BK][BN + 4];
  const int tid = threadIdx.x;
  const int bm = blockIdx.y * BM;
  const int bn = blockIdx.x * BN;
  const int tr = (tid / (BN / TN)) * TM;
  const int tc = (tid % (BN / TN)) * TN;
  float acc[TM][TN] = {};
  for (int k0 = 0; k0 < K; k0 += BK) {
    constexpr int A_F4 = BM * BK / 4;
#pragma unroll
    for (int u = 0; u < A_F4 / THREADS; ++u) {
      const int i = tid + u * THREADS;
      const int row = i / (BK / 4);
      const int c4 = (i % (BK / 4)) * 4;
      const float4 v =
          *(const float4*)(A + (size_t)(bm + row) * lda + k0 + c4);
      As[c4 + 0][row] = v.x;
      As[c4 + 1][row] = v.y;
      As[c4 + 2][row] = v.z;
      As[c4 + 3][row] = v.w;
    }
    constexpr int B_F4 = BK * BN / 4;
#pragma unroll
    for (int u = 0; u < B_F4 / THREADS; ++u) {
      const int i = tid + u * THREADS;
      const int row = i / (BN / 4);
      const int c4 = (i % (BN / 4)) * 4;
      *(float4*)(&Bs[row][c4]) =
          *(const float4*)(Bm + (size_t)(k0 + row) * ldb + bn + c4);
    }
    __syncthreads();
#pragma unroll
    for (int k = 0; k < BK; ++k) {
      float a[TM], b[TN];
#pragma unroll
      for (int i = 0; i < TM; i += 4)
        *(float4*)&a[i] = *(const float4*)&As[k][tr + i];
#pragma unroll
      for (int j = 0; j < TN; j += 4)
        *(float4*)&b[j] = *(const float4*)&Bs[k][tc + j];
#pragma unroll
      for (int i = 0; i < TM; ++i) {
#pragma unroll
        for (int j = 0; j < TN; ++j) acc[i][j] = fmaf(a[i], b[j], acc[i][j]);
      }
    }
    __syncthreads();
  }
#pragma unroll
  for (int i = 0; i < TM; ++i) {
#pragma unroll
    for (int j = 0; j < TN; j += 4) {
      *(float4*)(C + (size_t)(bm + tr + i) * ldc + bn + tc + j) = make_float4(
          acc[i][j], acc[i][j + 1], acc[i][j + 2], acc[i][j + 3]);
    }
  }
}

// ---------------- RMS norm, width 1536, in place -----------------------------
__global__ __launch_bounds__(256) void rmsq_kernel(
    float* __restrict__ x, const float* __restrict__ wt) {
  float* p = x + (size_t)blockIdx.x * kQLora;
  const int tid = threadIdx.x;
  float v[6];
  float ss = 0.f;
#pragma unroll
  for (int k = 0; k < 6; ++k) {
    v[k] = p[tid + 256 * k];
    ss += v[k] * v[k];
  }
#pragma unroll
  for (int off = 32; off > 0; off >>= 1) ss += __shfl_xor(ss, off);
  __shared__ float red[4];
  const int wid = tid >> 6, lane = tid & 63;
  if (lane == 0) red[wid] = ss;
  __syncthreads();
  const float tot = red[0] + red[1] + red[2] + red[3];
  const float r = rsqrtf(tot * (1.0f / kQLora) + kEps);
#pragma unroll
  for (int k = 0; k < 6; ++k)
    p[tid + 256 * k] = v[k] * r * wt[tid + 256 * k];
}

// ---------------- RMS norm, width 128 (cols 0..127 of ckv), in place --------
__global__ __launch_bounds__(128) void rmskv_kernel(
    float* __restrict__ ckv, const float* __restrict__ wt) {
  float* p = ckv + (size_t)blockIdx.x * kCkvDim;
  const int tid = threadIdx.x;
  const float v = p[tid];
  float ss = v * v;
#pragma unroll
  for (int off = 32; off > 0; off >>= 1) ss += __shfl_xor(ss, off);
  __shared__ float red[2];
  if ((tid & 63) == 0) red[tid >> 6] = ss;
  __syncthreads();
  const float tot = red[0] + red[1];
  const float r = rsqrtf(tot * (1.0f / 128.0f) + kEps);
  p[tid] = v * r * wt[tid];
}

// ---------------- RoPE on k_rot (ckv cols 128..191), in place ---------------
__global__ __launch_bounds__(256) void ropek_kernel(
    float* __restrict__ ckv, const float* __restrict__ cosb,
    const float* __restrict__ sinb) {
  const int idx = blockIdx.x * 256 + threadIdx.x;  // 0 .. BS*32
  const int t = idx >> 5, j = idx & 31;
  float* r = ckv + (size_t)t * kCkvDim + 128;
  const float x1 = r[j], x2 = r[j + 32];
  const float c1 = cosb[t * 64 + j], s1 = sinb[t * 64 + j];
  const float c2 = cosb[t * 64 + j + 32], s2 = sinb[t * 64 + j + 32];
  r[j] = x1 * c1 - x2 * s1;
  r[j + 32] = x2 * c2 + x1 * s2;
}

// ------ RoPE on q_rot + pre-scale all of q by SCALING, in place -------------
__global__ __launch_bounds__(256) void ropeq_kernel(
    float* __restrict__ q, const float* __restrict__ cosb,
    const float* __restrict__ sinb) {
  const int t = blockIdx.x;
  float* p = q + (size_t)t * kQDim;
  const float* cp = cosb + (size_t)t * 64;
  const float* sp = sinb + (size_t)t * 64;
  const int tid = threadIdx.x;
  // rot pairs: 16 heads * 32 pairs = 512
#pragma unroll
  for (int k = 0; k < 2; ++k) {
    const int pi = tid + 256 * k;
    const int h = pi >> 5, j = pi & 31;
    float* r = p + h * 192 + 128;
    const float x1 = r[j], x2 = r[j + 32];
    const float c1 = cp[j], s1 = sp[j];
    const float c2 = cp[j + 32], s2 = sp[j + 32];
    r[j] = (x1 * c1 - x2 * s1) * kScaling;
    r[j + 32] = (x2 * c2 + x1 * s2) * kScaling;
  }
  // pass part: 16 heads * 128 dims = 2048
#pragma unroll
  for (int k = 0; k < 8; ++k) {
    const int ei = tid + 256 * k;
    const int h = ei >> 7, d = ei & 127;
    p[h * 192 + d] *= kScaling;
  }
}

// ---------------- raw scores: weights[bh][qi][ki] = q . key -----------------
// q pre-scaled, so no extra scale here. keys: d<128 from kv, d>=128 from ckv.
__global__ __launch_bounds__(256) void scores_kernel(
    const float* __restrict__ q, const float* __restrict__ kv,
    const float* __restrict__ ckv, float* __restrict__ wout) {
  const int bh = blockIdx.z;
  const int b = bh >> 4, h = bh & 15;
  const int q0 = blockIdx.y * 128, k0 = blockIdx.x * 128;
  const int tid = threadIdx.x;
  __shared__ float Qs[16][128];
  __shared__ float Ks[16][132];
  const float* qbase = q + (size_t)b * kS * kQDim + h * 192;
  const float* kvbase = kv + (size_t)b * kS * kKVDim + h * 192;
  const float* ckvbase = ckv + (size_t)b * kS * kCkvDim;
  const int tr = (tid >> 4) * 8, tc = (tid & 15) * 8;
  float acc[8][8] = {};
  for (int kc = 0; kc < 12; ++kc) {
    const int kk0 = kc * 16;
#pragma unroll
    for (int u = 0; u < 2; ++u) {
      const int i = tid + u * 256;
      const int row = i >> 2, c4 = (i & 3) * 4;
      const float4 v =
          *(const float4*)(qbase + (size_t)(q0 + row) * kQDim + kk0 + c4);
      Qs[c4 + 0][row] = v.x;
      Qs[c4 + 1][row] = v.y;
      Qs[c4 + 2][row] = v.z;
      Qs[c4 + 3][row] = v.w;
    }
    const float* kb;
    int kst;
    if (kk0 < 128) {
      kb = kvbase + kk0;
      kst = kKVDim;
    } else {
      kb = ckvbase + kk0;
      kst = kCkvDim;
    }
#pragma unroll
    for (int u = 0; u < 2; ++u) {
      const int i = tid + u * 256;
      const int row = i >> 2, c4 = (i & 3) * 4;
      const float4 v = *(const float4*)(kb + (size_t)(k0 + row) * kst + c4);
      Ks[c4 + 0][row] = v.x;
      Ks[c4 + 1][row] = v.y;
      Ks[c4 + 2][row] = v.z;
      Ks[c4 + 3][row] = v.w;
    }
    __syncthreads();
#pragma unroll
    for (int k = 0; k < 16; ++k) {
      float a[8], bb[8];
      *(float4*)&a[0] = *(const float4*)&Qs[k][tr];
      *(float4*)&a[4] = *(const float4*)&Qs[k][tr + 4];
      *(float4*)&bb[0] = *(const float4*)&Ks[k][tc];
      *(float4*)&bb[4] = *(const float4*)&Ks[k][tc + 4];
#pragma unroll
      for (int i = 0; i < 8; ++i) {
#pragma unroll
        for (int j = 0; j < 8; ++j) acc[i][j] = fmaf(a[i], bb[j], acc[i][j]);
      }
    }
    __syncthreads();
  }
  float* wrow = wout + ((size_t)bh * kS + q0 + tr) * kS + k0 + tc;
#pragma unroll
  for (int i = 0; i < 8; ++i) {
    *(float4*)(wrow + (size_t)i * kS) =
        make_float4(acc[i][0], acc[i][1], acc[i][2], acc[i][3]);
    *(float4*)(wrow + (size_t)i * kS + 4) =
        make_float4(acc[i][4], acc[i][5], acc[i][6], acc[i][7]);
  }
}

// ---------------- row softmax in place, row length 2048 ---------------------
__global__ __launch_bounds__(256) void softmax_kernel(float* __restrict__ w) {
  float* p = w + (size_t)blockIdx.x * kS;
  const int tid = threadIdx.x;
  float4 v0 = *(const float4*)(p + tid * 8);
  float4 v1 = *(const float4*)(p + tid * 8 + 4);
  float m = fmaxf(fmaxf(fmaxf(v0.x, v0.y), fmaxf(v0.z, v0.w)),
                  fmaxf(fmaxf(v1.x, v1.y), fmaxf(v1.z, v1.w)));
#pragma unroll
  for (int off = 32; off > 0; off >>= 1) m = fmaxf(m, __shfl_xor(m, off));
  __shared__ float smax[4];
  __shared__ float ssum[4];
  const int wid = tid >> 6, lane = tid & 63;
  if (lane == 0) smax[wid] = m;
  __syncthreads();
  m = fmaxf(fmaxf(smax[0], smax[1]), fmaxf(smax[2], smax[3]));
  float e[8];
  e[0] = __expf(v0.x - m);
  e[1] = __expf(v0.y - m);
  e[2] = __expf(v0.z - m);
  e[3] = __expf(v0.w - m);
  e[4] = __expf(v1.x - m);
  e[5] = __expf(v1.y - m);
  e[6] = __expf(v1.z - m);
  e[7] = __expf(v1.w - m);
  float s = 0.f;
#pragma unroll
  for (int k = 0; k < 8; ++k) s += e[k];
#pragma unroll
  for (int off = 32; off > 0; off >>= 1) s += __shfl_xor(s, off);
  if (lane == 0) ssum[wid] = s;
  __syncthreads();
  s = ssum[0] + ssum[1] + ssum[2] + ssum[3];
  const float inv = 1.0f / s;
  *(float4*)(p + tid * 8) =
      make_float4(e[0] * inv, e[1] * inv, e[2] * inv, e[3] * inv);
  *(float4*)(p + tid * 8 + 4) =
      make_float4(e[4] * inv, e[5] * inv, e[6] * inv, e[7] * inv);
}

// ---------------- attn = weights @ v ----------------------------------------
// v[ki][e] lives at kv[(b*S+ki)*3072 + h*192 + 128 + e].
// attn written as [b*S + qi][h*64 + e] so the O-proj GEMM is a plain GEMM.
__global__ __launch_bounds__(256) void pv_kernel(
    const float* __restrict__ w, const float* __restrict__ kv,
    float* __restrict__ attn) {
  const int bh = blockIdx.z;
  const int b = bh >> 4, h = bh & 15;
  const int q0 = blockIdx.x * 128;
  const int tid = threadIdx.x;
  __shared__ float Ws[32][128];
  __shared__ float Vs[32][68];
  const float* wbase = w + (size_t)bh * kS * kS;
  const float* vbase = kv + (size_t)b * kS * kKVDim + h * 192 + 128;
  const int tr = (tid >> 4) * 8, tc = (tid & 15) * 4;
  float acc[8][4] = {};
  for (int kc = 0; kc < kS; kc += 32) {
#pragma unroll
    for (int u = 0; u < 4; ++u) {
      const int i = tid + u * 256;  // 1024 float4 = 128 rows x 32 cols
      const int row = i >> 3, c4 = (i & 7) * 4;
      const float4 v =
          *(const float4*)(wbase + (size_t)(q0 + row) * kS + kc + c4);
      Ws[c4 + 0][row] = v.x;
      Ws[c4 + 1][row] = v.y;
      Ws[c4 + 2][row] = v.z;
      Ws[c4 + 3][row] = v.w;
    }
#pragma unroll
    for (int u = 0; u < 2; ++u) {
      const int i = tid + u * 256;  // 512 float4 = 32 rows x 64 cols
      const int row = i >> 4, c4 = (i & 15) * 4;
      *(float4*)&Vs[row][c4] =
          *(const float4*)(vbase + (size_t)(kc + row) * kKVDim + c4);
    }
    __syncthreads();
#pragma unroll
    for (int k = 0; k < 32; ++k) {
      float a[8];
      *(float4*)&a[0] = *(const float4*)&Ws[k][tr];
      *(float4*)&a[4] = *(const float4*)&Ws[k][tr + 4];
      float bb[4];
      *(float4*)&bb[0] = *(const float4*)&Vs[k][tc];
#pragma unroll
      for (int i = 0; i < 8; ++i) {
#pragma unroll
        for (int j = 0; j < 4; ++j) acc[i][j] = fmaf(a[i], bb[j], acc[i][j]);
      }
    }
    __syncthreads();
  }
#pragma unroll
  for (int i = 0; i < 8; ++i) {
    *(float4*)(attn + (size_t)(b * kS + q0 + tr + i) * 1024 + h * 64 + tc) =
        make_float4(acc[i][0], acc[i][1], acc[i][2], acc[i][3]);
  }
}

}  // namespace

extern "C" void kernel_launch(void* const* d_in, const int* in_sizes, int n_in,
                              void* d_out, int out_size, void* d_ws,
                              size_t ws_size, hipStream_t stream) {
  const float* hidden = (const float*)d_in[0];
  const float* cosb = (const float*)d_in[1];
  const float* sinb = (const float*)d_in[2];
  const float* q_a_w = (const float*)d_in[3];
  const float* q_a_ln = (const float*)d_in[4];
  const float* q_b_w = (const float*)d_in[5];
  const float* kv_a_w = (const float*)d_in[6];
  const float* kv_a_ln = (const float*)d_in[7];
  const float* kv_b_w = (const float*)d_in[8];
  const float* o_w = (const float*)d_in[9];

  float* out = (float*)d_out;                         // [4096][2048]
  float* weights = out + (size_t)kBS * kHid;          // [B*H*S][S]
  float* ws = (float*)d_ws;
  // layout: [q_a | attn (reused)] [q] [ckv] [kv]  -> 129 MB total
  float* q_a = ws;                                    // [4096][1536]
  float* attn = ws;                                   // [4096][1024] (q_a dead)
  float* q = q_a + (size_t)kBS * kQLora;              // [4096][3072]
  float* ckv = q + (size_t)kBS * kQDim;               // [4096][192]
  float* kv = ckv + (size_t)kBS * kCkvDim;            // [4096][3072]

  const dim3 blk(256);
  // 1: q_a = hidden @ q_a_w
  sgemm_kernel<128, 128, 16, 8, 8>
      <<<dim3(kQLora / 128, kBS / 128), blk, 0, stream>>>(
          hidden, kHid, q_a_w, kQLora, q_a, kQLora, kHid);
  // 2: ckv = hidden @ kv_a_w
  sgemm_kernel<64, 64, 16, 4, 4>
      <<<dim3(kCkvDim / 64, kBS / 64), blk, 0, stream>>>(
          hidden, kHid, kv_a_w, kCkvDim, ckv, kCkvDim, kHid);
  // 3: rms_norm(q_a)
  rmsq_kernel<<<kBS, 256, 0, stream>>>(q_a, q_a_ln);
  // 4: rms_norm(ckv[:, :128])
  rmskv_kernel<<<kBS, 128, 0, stream>>>(ckv, kv_a_ln);
  // 5: rope on ckv[:, 128:192]
  ropek_kernel<<<kBS * 32 / 256, 256, 0, stream>>>(ckv, cosb, sinb);
  // 6: q = q_a @ q_b_w
  sgemm_kernel<128, 128, 16, 8, 8>
      <<<dim3(kQDim / 128, kBS / 128), blk, 0, stream>>>(
          q_a, kQLora, q_b_w, kQDim, q, kQDim, kQLora);
  // 7: kv = ckv[:, :128] @ kv_b_w
  sgemm_kernel<128, 128, 16, 8, 8>
      <<<dim3(kKVDim / 128, kBS / 128), blk, 0, stream>>>(
          ckv, kCkvDim, kv_b_w, kKVDim, kv, kKVDim, 128);
  // 8: rope + pre-scale q
  ropeq_kernel<<<kBS, 256, 0, stream>>>(q, cosb, sinb);
  // 9: raw scores into the attn_weights output region
  scores_kernel<<<dim3(kS / 128, kS / 128, kB * kH), blk, 0, stream>>>(
      q, kv, ckv, weights);
  // 10: softmax rows in place
  softmax_kernel<<<kB * kH * kS, 256, 0, stream>>>(weights);
  // 11: attn = weights @ v
  pv_kernel<<<dim3(kS / 128, 1, kB * kH), blk, 0, stream>>>(weights, kv, attn);
  // 12: out = attn @ o_w
  sgemm_kernel<128, 128, 16, 8, 8>
      <<<dim3(kHid / 128, kBS / 128), blk, 0, stream>>>(
          attn, 1024, o_w, kHid, out, kHid, 1024);
}

// Round 2
// 1262.439 us; speedup vs baseline: 2.2353x; 2.2353x over previous
//
#include <hip/hip_runtime.h>
#include <hip/hip_bf16.h>

// ============================================================================
// MLA forward, round 2: all GEMMs on bf16 MFMA (fp32 accumulate).
// Fragment layout for v_mfma_f32_16x16x32_bf16 (per cdna_hip guide / m89):
//   A: lane l, elem j (0..7)  -> A[l&15][8*(l>>4)+j]
//   B: lane l, elem j         -> B[8*(l>>4)+j][l&15]   (== A-layout on B^T)
//   C/D: lane l, reg j        -> row=(l>>4)*4+j, col=l&15
// Both LDS operands stored [row-or-col][K] with +8-short pad (2-way bank
// aliasing only => free). Weights pre-transposed+cvt to bf16 once per call.
// ============================================================================

namespace {

typedef __attribute__((ext_vector_type(8))) short short8;
typedef __attribute__((ext_vector_type(4))) float f32x4;

constexpr int kB = 2;
constexpr int kS = 2048;
constexpr int kHid = 2048;
constexpr int kH = 16;
constexpr int kQLora = 1536;
constexpr int kCkvDim = 192;
constexpr int kQDim = 3072;
constexpr int kKVDim = 3072;
constexpr int kBS = kB * kS;  // 4096
constexpr float kEps = 1e-6f;
constexpr float kScaling = 0.07216878364870322f;  // 192^-0.5

__device__ inline float bf2f(ushort u) {
  return __uint_as_float(((uint32_t)u) << 16);
}
__device__ inline ushort f2bf(float f) {  // RNE, finite inputs
  uint32_t u = __float_as_uint(f);
  return (ushort)((u + 0x7fffu + ((u >> 16) & 1u)) >> 16);
}

// ---------------- transpose + cvt: out[c][r] = bf16(in[r][c]) ---------------
__global__ __launch_bounds__(256) void tcvt_k(const float* __restrict__ in,
                                              ushort* __restrict__ out, int R,
                                              int C) {
  __shared__ float t[32][33];
  const int tx = threadIdx.x & 31, ty = threadIdx.x >> 5;
  const int c0 = blockIdx.x * 32, r0 = blockIdx.y * 32;
#pragma unroll
  for (int i = 0; i < 4; ++i)
    t[ty + i * 8][tx] = in[(size_t)(r0 + ty + i * 8) * C + c0 + tx];
  __syncthreads();
#pragma unroll
  for (int i = 0; i < 4; ++i)
    out[(size_t)(c0 + ty + i * 8) * R + r0 + tx] = f2bf(t[tx][ty + i * 8]);
}

// ---------------- generic MFMA GEMM: C = A(MxK) @ BT(NxK)^T -----------------
// A: fp32 (AF32) or bf16. BT bf16 [N][K]. C bf16 or fp32 per OUTF32.
template <int BM, int BN, bool AF32, bool OUTF32>
__global__ __launch_bounds__(256) void gemm_k(const void* __restrict__ Ap,
                                              int lda,
                                              const ushort* __restrict__ BT,
                                              int ldb, void* __restrict__ Cp,
                                              int ldc, int K) {
  __shared__ ushort As[BM][40];
  __shared__ ushort Bs[BN][40];
  const int tid = threadIdx.x;
  const int bm = blockIdx.y * BM, bn = blockIdx.x * BN;
  const int lane = tid & 63, wid = tid >> 6;
  constexpr int WR = BM / 2, WC = BN / 2, FM = WR / 16, FN = WC / 16;
  const int wr = (wid >> 1) * WR, wc = (wid & 1) * WC;
  const int r0 = lane & 15, g = lane >> 4;
  f32x4 acc[FM][FN];
#pragma unroll
  for (int m = 0; m < FM; ++m)
#pragma unroll
    for (int n = 0; n < FN; ++n) acc[m][n] = (f32x4){0.f, 0.f, 0.f, 0.f};

  for (int k0 = 0; k0 < K; k0 += 32) {
#pragma unroll
    for (int u = 0; u < BM * 4 / 256; ++u) {
      const int c = tid + u * 256;
      const int row = c >> 2, cp = c & 3;
      if constexpr (AF32) {
        const float* s =
            (const float*)Ap + (size_t)(bm + row) * lda + k0 + cp * 8;
        const float4 v0 = *(const float4*)s;
        const float4 v1 = *(const float4*)(s + 4);
        short8 o;
        o[0] = (short)f2bf(v0.x); o[1] = (short)f2bf(v0.y);
        o[2] = (short)f2bf(v0.z); o[3] = (short)f2bf(v0.w);
        o[4] = (short)f2bf(v1.x); o[5] = (short)f2bf(v1.y);
        o[6] = (short)f2bf(v1.z); o[7] = (short)f2bf(v1.w);
        *(short8*)&As[row][cp * 8] = o;
      } else {
        *(short8*)&As[row][cp * 8] = *(const short8*)((const ushort*)Ap +
                                                      (size_t)(bm + row) * lda +
                                                      k0 + cp * 8);
      }
    }
#pragma unroll
    for (int u = 0; u < BN * 4 / 256; ++u) {
      const int c = tid + u * 256;
      const int row = c >> 2, cp = c & 3;
      *(short8*)&Bs[row][cp * 8] =
          *(const short8*)(BT + (size_t)(bn + row) * ldb + k0 + cp * 8);
    }
    __syncthreads();
    short8 a[FM], b[FN];
#pragma unroll
    for (int m = 0; m < FM; ++m)
      a[m] = *(const short8*)&As[wr + m * 16 + r0][g * 8];
#pragma unroll
    for (int n = 0; n < FN; ++n)
      b[n] = *(const short8*)&Bs[wc + n * 16 + r0][g * 8];
#pragma unroll
    for (int m = 0; m < FM; ++m)
#pragma unroll
      for (int n = 0; n < FN; ++n)
        acc[m][n] = __builtin_amdgcn_mfma_f32_16x16x32_bf16(a[m], b[n],
                                                            acc[m][n], 0, 0, 0);
    __syncthreads();
  }
#pragma unroll
  for (int m = 0; m < FM; ++m) {
    const int row = bm + wr + m * 16 + g * 4;
#pragma unroll
    for (int n = 0; n < FN; ++n) {
      const int col = bn + wc + n * 16 + r0;
#pragma unroll
      for (int j = 0; j < 4; ++j) {
        if constexpr (OUTF32)
          ((float*)Cp)[(size_t)(row + j) * ldc + col] = acc[m][n][j];
        else
          ((ushort*)Cp)[(size_t)(row + j) * ldc + col] = f2bf(acc[m][n][j]);
      }
    }
  }
}

// ---------------- RMS norm width 1536, bf16 in place ------------------------
__global__ __launch_bounds__(192) void rmsq_k(ushort* __restrict__ x,
                                              const float* __restrict__ wt) {
  ushort* p = x + (size_t)blockIdx.x * kQLora;
  const int tid = threadIdx.x;
  const short8 v = *(const short8*)(p + tid * 8);
  float f[8];
  float ss = 0.f;
#pragma unroll
  for (int i = 0; i < 8; ++i) {
    f[i] = bf2f((ushort)v[i]);
    ss += f[i] * f[i];
  }
#pragma unroll
  for (int off = 32; off > 0; off >>= 1) ss += __shfl_xor(ss, off);
  __shared__ float red[3];
  if ((tid & 63) == 0) red[tid >> 6] = ss;
  __syncthreads();
  const float tot = red[0] + red[1] + red[2];
  const float r = rsqrtf(tot * (1.0f / kQLora) + kEps);
  const float4 w0 = *(const float4*)(wt + tid * 8);
  const float4 w1 = *(const float4*)(wt + tid * 8 + 4);
  short8 o;
  o[0] = (short)f2bf(f[0] * r * w0.x); o[1] = (short)f2bf(f[1] * r * w0.y);
  o[2] = (short)f2bf(f[2] * r * w0.z); o[3] = (short)f2bf(f[3] * r * w0.w);
  o[4] = (short)f2bf(f[4] * r * w1.x); o[5] = (short)f2bf(f[5] * r * w1.y);
  o[6] = (short)f2bf(f[6] * r * w1.z); o[7] = (short)f2bf(f[7] * r * w1.w);
  *(short8*)(p + tid * 8) = o;
}

// ---------------- RMS norm on ckv cols 0..127, bf16 in place ----------------
__global__ __launch_bounds__(128) void rmskv_k(ushort* __restrict__ x,
                                               const float* __restrict__ wt) {
  ushort* p = x + (size_t)blockIdx.x * kCkvDim;
  const int tid = threadIdx.x;
  const float f = bf2f(p[tid]);
  float ss = f * f;
#pragma unroll
  for (int off = 32; off > 0; off >>= 1) ss += __shfl_xor(ss, off);
  __shared__ float red[2];
  if ((tid & 63) == 0) red[tid >> 6] = ss;
  __syncthreads();
  const float r = rsqrtf((red[0] + red[1]) * (1.0f / 128.0f) + kEps);
  p[tid] = f2bf(f * r * wt[tid]);
}

// ---------------- k_rot rope: ckv cols 128..191 -> krot [4096][64] ----------
__global__ __launch_bounds__(256) void krot_k(const ushort* __restrict__ ckv,
                                              const float* __restrict__ cosb,
                                              const float* __restrict__ sinb,
                                              ushort* __restrict__ kr) {
  const int i = blockIdx.x * 256 + threadIdx.x;
  const int t = i >> 5, j = i & 31;
  const ushort* r = ckv + (size_t)t * kCkvDim + 128;
  const float x1 = bf2f(r[j]), x2 = bf2f(r[j + 32]);
  const float c1 = cosb[t * 64 + j], s1 = sinb[t * 64 + j];
  const float c2 = cosb[t * 64 + j + 32], s2 = sinb[t * 64 + j + 32];
  kr[(size_t)t * 64 + j] = f2bf(x1 * c1 - x2 * s1);
  kr[(size_t)t * 64 + j + 32] = f2bf(x2 * c2 + x1 * s2);
}

// ------ rope q_rot + pre-scale all of q by SCALING, bf16 in place -----------
__global__ __launch_bounds__(256) void ropeq_k(ushort* __restrict__ q,
                                               const float* __restrict__ cosb,
                                               const float* __restrict__ sinb) {
  const int t = blockIdx.x;
  ushort* p = q + (size_t)t * kQDim;
  const float* cb = cosb + (size_t)t * 64;
  const float* sb = sinb + (size_t)t * 64;
  const int tid = threadIdx.x;
#pragma unroll
  for (int u = 0; u < 2; ++u) {
    const int pi = tid + u * 256;
    const int h = pi >> 5, j = pi & 31;
    ushort* r = p + h * 192 + 128;
    const float x1 = bf2f(r[j]), x2 = bf2f(r[j + 32]);
    const float c1 = cb[j], s1 = sb[j], c2 = cb[j + 32], s2 = sb[j + 32];
    r[j] = f2bf((x1 * c1 - x2 * s1) * kScaling);
    r[j + 32] = f2bf((x2 * c2 + x1 * s2) * kScaling);
  }
  {
    const int h = tid >> 4, cp = tid & 15;
    ushort* r = p + h * 192 + cp * 8;
    const short8 v = *(const short8*)r;
    short8 o;
#pragma unroll
    for (int i = 0; i < 8; ++i)
      o[i] = (short)f2bf(bf2f((ushort)v[i]) * kScaling);
    *(short8*)r = o;
  }
}

// ---- v transpose: vT[(bh*64+e)][ki] = kvb[(b*S+ki)][h*192+128+e] -----------
__global__ __launch_bounds__(256) void vtr_k(const ushort* __restrict__ kvb,
                                             ushort* __restrict__ vT) {
  __shared__ ushort t[64][72];
  const int bh = blockIdx.y, b = bh >> 4, h = bh & 15;
  const int ki0 = blockIdx.x * 64;
  const int tid = threadIdx.x;
#pragma unroll
  for (int u = 0; u < 2; ++u) {
    const int c = tid + u * 256;
    const int row = c >> 3, cp = c & 7;
    *(short8*)&t[row][cp * 8] =
        *(const short8*)(kvb + (size_t)(b * kS + ki0 + row) * kKVDim + h * 192 +
                         128 + cp * 8);
  }
  __syncthreads();
#pragma unroll
  for (int u = 0; u < 2; ++u) {
    const int c = tid + u * 256;
    const int e = c & 63, cp = c >> 6;
    short8 s;
#pragma unroll
    for (int i = 0; i < 8; ++i) s[i] = (short)t[cp * 8 + i][e];
    *(short8*)(vT + (size_t)(bh * 64 + e) * kS + ki0 + cp * 8) = s;
  }
}

// ---------------- scores (bf16 MFMA) -> fp32 weights ------------------------
__global__ __launch_bounds__(256) void scores_k(const ushort* __restrict__ q,
                                                const ushort* __restrict__ kvb,
                                                const ushort* __restrict__ krot,
                                                float* __restrict__ w) {
  __shared__ ushort Qs[128][40];
  __shared__ ushort Ks[128][40];
  const int tid = threadIdx.x;
  const int bh = blockIdx.z, b = bh >> 4, h = bh & 15;
  const int q0 = blockIdx.y * 128, k0 = blockIdx.x * 128;
  const int lane = tid & 63, wid = tid >> 6;
  const int wr = (wid >> 1) * 64, wc = (wid & 1) * 64;
  const int r0 = lane & 15, g = lane >> 4;
  f32x4 acc[4][4];
#pragma unroll
  for (int m = 0; m < 4; ++m)
#pragma unroll
    for (int n = 0; n < 4; ++n) acc[m][n] = (f32x4){0.f, 0.f, 0.f, 0.f};
  const ushort* qbase = q + (size_t)(b * kS + q0) * kQDim + h * 192;
  const ushort* kbase = kvb + (size_t)(b * kS + k0) * kKVDim + h * 192;
  const ushort* rbase = krot + (size_t)(b * kS + k0) * 64;
  for (int kc = 0; kc < 6; ++kc) {
    const int kk = kc * 32;
#pragma unroll
    for (int u = 0; u < 2; ++u) {
      const int c = tid + u * 256;
      const int row = c >> 2, cp = c & 3;
      *(short8*)&Qs[row][cp * 8] =
          *(const short8*)(qbase + (size_t)row * kQDim + kk + cp * 8);
    }
#pragma unroll
    for (int u = 0; u < 2; ++u) {
      const int c = tid + u * 256;
      const int row = c >> 2, cp = c & 3;
      const ushort* src = (kc < 4)
                              ? kbase + (size_t)row * kKVDim + kk + cp * 8
                              : rbase + (size_t)row * 64 + (kk - 128) + cp * 8;
      *(short8*)&Ks[row][cp * 8] = *(const short8*)src;
    }
    __syncthreads();
    short8 a[4], bb[4];
#pragma unroll
    for (int m = 0; m < 4; ++m)
      a[m] = *(const short8*)&Qs[wr + m * 16 + r0][g * 8];
#pragma unroll
    for (int n = 0; n < 4; ++n)
      bb[n] = *(const short8*)&Ks[wc + n * 16 + r0][g * 8];
#pragma unroll
    for (int m = 0; m < 4; ++m)
#pragma unroll
      for (int n = 0; n < 4; ++n)
        acc[m][n] = __builtin_amdgcn_mfma_f32_16x16x32_bf16(a[m], bb[n],
                                                            acc[m][n], 0, 0, 0);
    __syncthreads();
  }
#pragma unroll
  for (int m = 0; m < 4; ++m) {
    const int row = q0 + wr + m * 16 + g * 4;
#pragma unroll
    for (int n = 0; n < 4; ++n) {
      const int col = k0 + wc + n * 16 + r0;
#pragma unroll
      for (int j = 0; j < 4; ++j)
        w[((size_t)bh * kS + row + j) * kS + col] = acc[m][n][j];
    }
  }
}

// ---------------- row softmax in place, fp32, row length 2048 ---------------
__global__ __launch_bounds__(256) void softmax_k(float* __restrict__ w) {
  float* p = w + (size_t)blockIdx.x * kS;
  const int tid = threadIdx.x;
  float4 v0 = *(const float4*)(p + tid * 8);
  float4 v1 = *(const float4*)(p + tid * 8 + 4);
  float m = fmaxf(fmaxf(fmaxf(v0.x, v0.y), fmaxf(v0.z, v0.w)),
                  fmaxf(fmaxf(v1.x, v1.y), fmaxf(v1.z, v1.w)));
#pragma unroll
  for (int off = 32; off > 0; off >>= 1) m = fmaxf(m, __shfl_xor(m, off));
  __shared__ float smax[4];
  __shared__ float ssum[4];
  const int wid = tid >> 6, lane = tid & 63;
  if (lane == 0) smax[wid] = m;
  __syncthreads();
  m = fmaxf(fmaxf(smax[0], smax[1]), fmaxf(smax[2], smax[3]));
  float e[8];
  e[0] = __expf(v0.x - m); e[1] = __expf(v0.y - m);
  e[2] = __expf(v0.z - m); e[3] = __expf(v0.w - m);
  e[4] = __expf(v1.x - m); e[5] = __expf(v1.y - m);
  e[6] = __expf(v1.z - m); e[7] = __expf(v1.w - m);
  float s = 0.f;
#pragma unroll
  for (int k = 0; k < 8; ++k) s += e[k];
#pragma unroll
  for (int off = 32; off > 0; off >>= 1) s += __shfl_xor(s, off);
  if (lane == 0) ssum[wid] = s;
  __syncthreads();
  s = ssum[0] + ssum[1] + ssum[2] + ssum[3];
  const float inv = 1.0f / s;
  *(float4*)(p + tid * 8) =
      make_float4(e[0] * inv, e[1] * inv, e[2] * inv, e[3] * inv);
  *(float4*)(p + tid * 8 + 4) =
      make_float4(e[4] * inv, e[5] * inv, e[6] * inv, e[7] * inv);
}

// ---------------- pv: attn = weights(f32, cvt) @ vT^T -----------------------
__global__ __launch_bounds__(256) void pv_k(const float* __restrict__ w,
                                            const ushort* __restrict__ vT,
                                            ushort* __restrict__ attn) {
  __shared__ ushort Ws[128][40];
  __shared__ ushort Vs[64][40];
  const int tid = threadIdx.x;
  const int bh = blockIdx.z, b = bh >> 4, h = bh & 15;
  const int q0 = blockIdx.x * 128;
  const int lane = tid & 63, wid = tid >> 6;
  const int wr = (wid >> 1) * 64, wc = (wid & 1) * 32;
  const int r0 = lane & 15, g = lane >> 4;
  f32x4 acc[4][2];
#pragma unroll
  for (int m = 0; m < 4; ++m)
#pragma unroll
    for (int n = 0; n < 2; ++n) acc[m][n] = (f32x4){0.f, 0.f, 0.f, 0.f};
  const float* wbase = w + ((size_t)bh * kS + q0) * kS;
  const ushort* vbase = vT + (size_t)bh * 64 * kS;
  for (int k0 = 0; k0 < kS; k0 += 32) {
#pragma unroll
    for (int u = 0; u < 2; ++u) {
      const int c = tid + u * 256;
      const int row = c >> 2, cp = c & 3;
      const float* s = wbase + (size_t)row * kS + k0 + cp * 8;
      const float4 v0 = *(const float4*)s;
      const float4 v1 = *(const float4*)(s + 4);
      short8 o;
      o[0] = (short)f2bf(v0.x); o[1] = (short)f2bf(v0.y);
      o[2] = (short)f2bf(v0.z); o[3] = (short)f2bf(v0.w);
      o[4] = (short)f2bf(v1.x); o[5] = (short)f2bf(v1.y);
      o[6] = (short)f2bf(v1.z); o[7] = (short)f2bf(v1.w);
      *(short8*)&Ws[row][cp * 8] = o;
    }
    {
      const int row = tid >> 2, cp = tid & 3;
      *(short8*)&Vs[row][cp * 8] =
          *(const short8*)(vbase + (size_t)row * kS + k0 + cp * 8);
    }
    __syncthreads();
    short8 a[4], bb[2];
#pragma unroll
    for (int m = 0; m < 4; ++m)
      a[m] = *(const short8*)&Ws[wr + m * 16 + r0][g * 8];
#pragma unroll
    for (int n = 0; n < 2; ++n)
      bb[n] = *(const short8*)&Vs[wc + n * 16 + r0][g * 8];
#pragma unroll
    for (int m = 0; m < 4; ++m)
#pragma unroll
      for (int n = 0; n < 2; ++n)
        acc[m][n] = __builtin_amdgcn_mfma_f32_16x16x32_bf16(a[m], bb[n],
                                                            acc[m][n], 0, 0, 0);
    __syncthreads();
  }
#pragma unroll
  for (int m = 0; m < 4; ++m) {
    const int row = b * kS + q0 + wr + m * 16 + g * 4;
#pragma unroll
    for (int n = 0; n < 2; ++n) {
      const int col = h * 64 + wc + n * 16 + r0;
#pragma unroll
      for (int j = 0; j < 4; ++j)
        attn[(size_t)(row + j) * 1024 + col] = f2bf(acc[m][n][j]);
    }
  }
}

}  // namespace

extern "C" void kernel_launch(void* const* d_in, const int* in_sizes, int n_in,
                              void* d_out, int out_size, void* d_ws,
                              size_t ws_size, hipStream_t stream) {
  const float* hidden = (const float*)d_in[0];
  const float* cosb = (const float*)d_in[1];
  const float* sinb = (const float*)d_in[2];
  const float* q_a_w = (const float*)d_in[3];
  const float* q_a_ln = (const float*)d_in[4];
  const float* q_b_w = (const float*)d_in[5];
  const float* kv_a_w = (const float*)d_in[6];
  const float* kv_a_ln = (const float*)d_in[7];
  const float* kv_b_w = (const float*)d_in[8];
  const float* o_w = (const float*)d_in[9];

  float* out = (float*)d_out;                 // [4096][2048] fp32
  float* weights = out + (size_t)kBS * kHid;  // [B*H*S][S] fp32

  ushort* ws = (ushort*)d_ws;
  ushort* q_a_wT = ws;                                   // [1536][2048]
  ushort* q_b_wT = q_a_wT + (size_t)1536 * 2048;         // [3072][1536]
  ushort* kv_a_wT = q_b_wT + (size_t)3072 * 1536;        // [192][2048]
  ushort* kv_b_wT = kv_a_wT + (size_t)192 * 2048;        // [3072][128]
  ushort* o_wT = kv_b_wT + (size_t)3072 * 128;           // [2048][1024]
  ushort* q_a = o_wT + (size_t)2048 * 1024;              // [4096][1536]
  ushort* qb = q_a + (size_t)kBS * kQLora;               // [4096][3072]
  ushort* ckv = qb + (size_t)kBS * kQDim;                // [4096][192]
  ushort* krot = ckv + (size_t)kBS * kCkvDim;            // [4096][64]
  ushort* kvb = krot + (size_t)kBS * 64;                 // [4096][3072]
  ushort* vT = kvb + (size_t)kBS * kKVDim;               // [32*64][2048]
  ushort* attn = vT + (size_t)kB * kH * 64 * kS;         // [4096][1024]

  const dim3 blk(256);
  // weight transposes + cvt
  tcvt_k<<<dim3(48, 64), blk, 0, stream>>>(q_a_w, q_a_wT, 2048, 1536);
  tcvt_k<<<dim3(96, 48), blk, 0, stream>>>(q_b_w, q_b_wT, 1536, 3072);
  tcvt_k<<<dim3(6, 64), blk, 0, stream>>>(kv_a_w, kv_a_wT, 2048, 192);
  tcvt_k<<<dim3(96, 4), blk, 0, stream>>>(kv_b_w, kv_b_wT, 128, 3072);
  tcvt_k<<<dim3(64, 32), blk, 0, stream>>>(o_w, o_wT, 1024, 2048);
  // q_a = hidden @ q_a_w           M=4096 N=1536 K=2048
  gemm_k<128, 128, true, false><<<dim3(12, 32), blk, 0, stream>>>(
      hidden, kHid, q_a_wT, 2048, q_a, kQLora, 2048);
  // ckv = hidden @ kv_a_w          M=4096 N=192 K=2048
  gemm_k<128, 64, true, false><<<dim3(3, 32), blk, 0, stream>>>(
      hidden, kHid, kv_a_wT, 2048, ckv, kCkvDim, 2048);
  rmsq_k<<<kBS, 192, 0, stream>>>(q_a, q_a_ln);
  rmskv_k<<<kBS, 128, 0, stream>>>(ckv, kv_a_ln);
  krot_k<<<kBS * 32 / 256, 256, 0, stream>>>(ckv, cosb, sinb, krot);
  // q = q_a @ q_b_w                M=4096 N=3072 K=1536
  gemm_k<128, 128, false, false><<<dim3(24, 32), blk, 0, stream>>>(
      q_a, kQLora, q_b_wT, 1536, qb, kQDim, 1536);
  ropeq_k<<<kBS, 256, 0, stream>>>(qb, cosb, sinb);
  // kv = ckv_n @ kv_b_w            M=4096 N=3072 K=128
  gemm_k<128, 128, false, false><<<dim3(24, 32), blk, 0, stream>>>(
      ckv, kCkvDim, kv_b_wT, 128, kvb, kKVDim, 128);
  vtr_k<<<dim3(32, 32), blk, 0, stream>>>(kvb, vT);
  // raw scores -> weights (q pre-scaled)
  scores_k<<<dim3(16, 16, 32), blk, 0, stream>>>(qb, kvb, krot, weights);
  softmax_k<<<kB * kH * kS, 256, 0, stream>>>(weights);
  pv_k<<<dim3(16, 1, 32), blk, 0, stream>>>(weights, vT, attn);
  // out = attn @ o_w               M=4096 N=2048 K=1024
  gemm_k<128, 128, false, true><<<dim3(16, 32), blk, 0, stream>>>(
      attn, 1024, o_wT, 1024, out, kHid, 1024);
}